// Round 2
// baseline (81.483 us; speedup 1.0000x reference)
//
#include <hip/hip_runtime.h>
#include <stdint.h>
#include <stddef.h>

// SIR scan: B=16384 batches, T=2048 steps, F=2 (beta,gamma), fp32.
// One thread owns one batch (64 lanes = 64 batches per block, 256 blocks
// = 1 wave/CU). Time chunks staged HBM->LDS via global_load_lds.
// Round 2: 4-deep software pipeline with COUNTED vmcnt (never drain to 0
// in the main loop) to stop paying HBM latency per chunk.

#define T_STEPS 2048
#define C_STEPS 32                   // timesteps per chunk
#define NCHUNK  (T_STEPS / C_STEPS)  // 64
#define BPB     64                   // batches per block == threads per block
#define PAIRS   (C_STEPS / 2)        // 16 float4 slots per batch per chunk
#define IPC     16                   // global_load_lds instrs per 16 KB chunk

#define INV_POP 1e-6f

// Stage chunk c of this block's 64 batches into lds (linear layout,
// 16B slot (i, q) <- global step-pair (q ^ (i&15)) of batch i).
// Instruction j covers 4 batch rows (4 x 256 B = 1 KB): lane l -> batch
// 4j + (l>>4), slot q = l&15, global pair p = q ^ (batch&15). The per-lane
// GLOBAL address carries the swizzle; LDS dest stays linear (rule #21).
__device__ __forceinline__ void stage_chunk(const float* __restrict__ in,
                                            float4* lds, int b0, int c, int lane)
{
    const int sub = lane >> 4;   // 0..3
    const int q   = lane & 15;
#pragma unroll
    for (int j = 0; j < IPC; ++j) {
        const int bi = 4 * j + sub;             // batch within block
        const int p  = q ^ (bi & 15);           // swizzled global pair index
        const float* g = in
            + (size_t)(b0 + bi) * (T_STEPS * 2)
            + (size_t)c * (C_STEPS * 2)
            + (size_t)(p * 4);
        float4* l = lds + j * 64;               // 1 KB per instruction, uniform
        __builtin_amdgcn_global_load_lds(
            (__attribute__((address_space(1))) void*)g,
            (__attribute__((address_space(3))) void*)l,
            16, 0, 0);
    }
}

// Consume one chunk: 16 ds_read_b128 per lane (8 lanes/bank = wave64-b128
// inherent minimum via the XOR swizzle), 32 recurrence steps in time order.
__device__ __forceinline__ void compute_chunk(const float4* lds, int tid,
                                              float& S, float& I, float& R)
{
    const int swz = tid & 15;
    const float4* row = lds + tid * PAIRS;
#pragma unroll
    for (int p = 0; p < PAIRS; ++p) {
        const float4 v = row[p ^ swz];   // steps 2p (v.x,v.y) and 2p+1 (v.z,v.w)

        float ni = S * I * (v.x * INV_POP);
        float nr = v.y * I;
        S = S - ni;
        I = I + ni - nr;
        R = R + nr;

        ni = S * I * (v.z * INV_POP);
        nr = v.w * I;
        S = S - ni;
        I = I + ni - nr;
        R = R + nr;
    }
}

#define WAIT32() asm volatile("s_waitcnt vmcnt(32)" ::: "memory")
#define WAIT16() asm volatile("s_waitcnt vmcnt(16)" ::: "memory")
#define WAIT0()  asm volatile("s_waitcnt vmcnt(0)"  ::: "memory")

__global__ __launch_bounds__(64)
void sir_scan_kernel(const float* __restrict__ in, const float* __restrict__ init,
                     float* __restrict__ out, int half)
{
    // 4 x 16 KB, statically distinct objects (precise LDS alias analysis)
    __shared__ float4 buf0[BPB * PAIRS];
    __shared__ float4 buf1[BPB * PAIRS];
    __shared__ float4 buf2[BPB * PAIRS];
    __shared__ float4 buf3[BPB * PAIRS];

    const int tid = threadIdx.x;           // 0..63, batch within block
    const int b0  = blockIdx.x * BPB;
    const int gb  = b0 + tid;

    float S = init[gb * 3 + 0];
    float I = init[gb * 3 + 1];
    float R = init[gb * 3 + 2];

    // prologue: 3 chunks in flight (48 loads)
    stage_chunk(in, buf0, b0, 0, tid);
    stage_chunk(in, buf1, b0, 1, tid);
    stage_chunk(in, buf2, b0, 2, tid);

    // main loop: chunks 0..NCHUNK-5, always 3 chunks in flight after stage.
    // vmcnt(32) == "the oldest of the 3 outstanding chunks has landed".
#pragma unroll 1
    for (int c = 0; c < NCHUNK - 4; c += 4) {
        WAIT32(); stage_chunk(in, buf3, b0, c + 3, tid);
        compute_chunk(buf0, tid, S, I, R);
        WAIT32(); stage_chunk(in, buf0, b0, c + 4, tid);
        compute_chunk(buf1, tid, S, I, R);
        WAIT32(); stage_chunk(in, buf1, b0, c + 5, tid);
        compute_chunk(buf2, tid, S, I, R);
        WAIT32(); stage_chunk(in, buf2, b0, c + 6, tid);
        compute_chunk(buf3, tid, S, I, R);
    }

    // epilogue: chunks NCHUNK-4 .. NCHUNK-1 (60..63), stage the last one
    WAIT32(); stage_chunk(in, buf3, b0, NCHUNK - 1, tid);
    compute_chunk(buf0, tid, S, I, R);       // chunk 60
    WAIT32();
    compute_chunk(buf1, tid, S, I, R);       // chunk 61
    WAIT16();
    compute_chunk(buf2, tid, S, I, R);       // chunk 62
    WAIT0();
    compute_chunk(buf3, tid, S, I, R);       // chunk 63

    // reference returns (final_state, final_state): write both halves
    out[gb * 3 + 0] = S;
    out[gb * 3 + 1] = I;
    out[gb * 3 + 2] = R;
    out[half + gb * 3 + 0] = S;
    out[half + gb * 3 + 1] = I;
    out[half + gb * 3 + 2] = R;
}

extern "C" void kernel_launch(void* const* d_in, const int* in_sizes, int n_in,
                              void* d_out, int out_size, void* d_ws, size_t ws_size,
                              hipStream_t stream) {
    (void)in_sizes; (void)n_in; (void)d_ws; (void)ws_size;
    const float* in   = (const float*)d_in[0];   // (B, T, 2) fp32
    const float* init = (const float*)d_in[1];   // (B, 3)    fp32
    float* out        = (float*)d_out;           // 2 x (B, 3) fp32, concatenated
    const int half = out_size / 2;

    dim3 grid(16384 / BPB);   // 256 blocks, 1 per CU
    dim3 block(BPB);          // 64 threads = 1 wave
    sir_scan_kernel<<<grid, block, 0, stream>>>(in, init, out, half);
}

// Round 3
// 57.450 us; speedup vs baseline: 1.4183x; 1.4183x over previous
//
#include <hip/hip_runtime.h>
#include <stdint.h>
#include <stddef.h>

// SIR scan: B=16384 batches, T=2048 steps, F=2 (beta,gamma), fp32.
// Round 3: producer/consumer wave specialization.
//   wave 0 (tid 0..63)  = consumer: owns 64 batches, runs the scan from LDS.
//   wave 1 (tid 64..127)= producer: issues all global_load_lds; counted
//                         vmcnt waits live ONLY on this wave's counter.
// Consumer has zero outstanding VMEM -> compiler-inserted vmcnt drains
// before its ds_reads (the round-1/2 serializer) are free.
// Sync: raw inline-asm s_barrier, one per chunk, lockstep.

#define T_STEPS 2048
#define C_STEPS 64                   // timesteps per chunk
#define NCHUNK  (T_STEPS / C_STEPS)  // 32
#define BPB     64                   // batches per block
#define PAIRS   (C_STEPS / 2)        // 32 float4 slots per batch per chunk
#define IPC     32                   // global_load_lds instrs per 32 KB chunk

#define INV_POP 1e-6f

// Stage chunk c of this block's 64 batches into lds (linear dest,
// swizzle carried by the per-lane GLOBAL address -- rule #21).
// Instruction j covers batches {2j, 2j+1}: lane l -> batch 2j + (l>>5),
// slot q = l&31, global pair p = q ^ (batch&15).
__device__ __forceinline__ void stage_chunk(const float* __restrict__ in,
                                            float4* lds, int b0, int c, int lane)
{
    const int hi = lane >> 5;   // 0 or 1
    const int q  = lane & 31;
#pragma unroll
    for (int j = 0; j < IPC; ++j) {
        const int bi = 2 * j + hi;              // batch within block
        const int p  = q ^ (bi & 15);           // swizzled global pair index
        const float* g = in
            + (size_t)(b0 + bi) * (T_STEPS * 2)
            + (size_t)c * (C_STEPS * 2)
            + (size_t)(p * 4);
        float4* l = lds + j * 64;               // 1 KB per instruction, uniform
        __builtin_amdgcn_global_load_lds(
            (__attribute__((address_space(1))) void*)g,
            (__attribute__((address_space(3))) void*)l,
            16, 0, 0);
    }
}

// Consume one chunk: 32 ds_read_b128 per lane (XOR swizzle -> 8 lanes/bank,
// the wave64-b128 inherent minimum), 64 recurrence steps in time order.
__device__ __forceinline__ void compute_chunk(const float4* lds, int tid,
                                              float& S, float& I, float& R)
{
    const int swz = tid & 15;
    const float4* row = lds + tid * PAIRS;
#pragma unroll
    for (int p = 0; p < PAIRS; ++p) {
        const float4 v = row[p ^ swz];   // steps 2p (v.x,v.y) and 2p+1 (v.z,v.w)

        float ni = S * I * (v.x * INV_POP);
        float nr = v.y * I;
        S = S - ni;
        I = I + ni - nr;
        R = R + nr;

        ni = S * I * (v.z * INV_POP);
        nr = v.w * I;
        S = S - ni;
        I = I + ni - nr;
        R = R + nr;
    }
}

#define BAR()   asm volatile("s_barrier" ::: "memory")
#define WAIT32() asm volatile("s_waitcnt vmcnt(32)" ::: "memory")
#define WAIT0()  asm volatile("s_waitcnt vmcnt(0)"  ::: "memory")

__global__ __launch_bounds__(128)
void sir_scan_kernel(const float* __restrict__ in, const float* __restrict__ init,
                     float* __restrict__ out, int half)
{
    // 4 x 32 KB = 128 KB (1 block/CU), statically distinct objects
    __shared__ float4 buf0[BPB * PAIRS];
    __shared__ float4 buf1[BPB * PAIRS];
    __shared__ float4 buf2[BPB * PAIRS];
    __shared__ float4 buf3[BPB * PAIRS];

    const int tid = threadIdx.x;
    const int b0  = blockIdx.x * BPB;

    if (tid < 64) {
        // ---------------- consumer wave: zero outstanding VMEM in the loop
        const int gb = b0 + tid;
        float S = init[gb * 3 + 0];
        float I = init[gb * 3 + 1];
        float R = init[gb * 3 + 2];

        // bar #c <=> "chunk c has landed" (producer waits before its bar)
#pragma unroll 1
        for (int c = 0; c < NCHUNK; c += 4) {
            BAR(); compute_chunk(buf0, tid, S, I, R);
            BAR(); compute_chunk(buf1, tid, S, I, R);
            BAR(); compute_chunk(buf2, tid, S, I, R);
            BAR(); compute_chunk(buf3, tid, S, I, R);
        }

        out[gb * 3 + 0] = S;
        out[gb * 3 + 1] = I;
        out[gb * 3 + 2] = R;
        out[half + gb * 3 + 0] = S;
        out[half + gb * 3 + 1] = I;
        out[half + gb * 3 + 2] = R;
    } else {
        // ---------------- producer wave: all staging + counted waits here
        const int lane = tid - 64;

        stage_chunk(in, buf0, b0, 0, lane);
        stage_chunk(in, buf1, b0, 1, lane);

        // invariant at each WAIT32: outstanding = {c, c+1} (64 instr);
        // vmcnt(32) => chunk c fully landed, chunk c+1 still in flight.
        // After BAR #c, consumer reads buf[c%4]; we then stage chunk c+2
        // into buf[(c+2)%4] = buf[(c-2)%4], which the consumer finished
        // two barriers ago (lockstep => write-after-read safe).
#pragma unroll 1
        for (int c = 0; c < NCHUNK - 4; c += 4) {
            WAIT32(); BAR(); stage_chunk(in, buf2, b0, c + 2, lane);
            WAIT32(); BAR(); stage_chunk(in, buf3, b0, c + 3, lane);
            WAIT32(); BAR(); stage_chunk(in, buf0, b0, c + 4, lane);
            WAIT32(); BAR(); stage_chunk(in, buf1, b0, c + 5, lane);
        }
        // last block: chunks 28..31, stage only 30,31
        WAIT32(); BAR(); stage_chunk(in, buf2, b0, NCHUNK - 2, lane);
        WAIT32(); BAR(); stage_chunk(in, buf3, b0, NCHUNK - 1, lane);
        WAIT32(); BAR();   // chunk 30 landed ({30,31} outstanding -> <=32)
        WAIT0();  BAR();   // chunk 31 landed
    }
}

extern "C" void kernel_launch(void* const* d_in, const int* in_sizes, int n_in,
                              void* d_out, int out_size, void* d_ws, size_t ws_size,
                              hipStream_t stream) {
    (void)in_sizes; (void)n_in; (void)d_ws; (void)ws_size;
    const float* in   = (const float*)d_in[0];   // (B, T, 2) fp32
    const float* init = (const float*)d_in[1];   // (B, 3)    fp32
    float* out        = (float*)d_out;           // 2 x (B, 3) fp32, concatenated
    const int half = out_size / 2;

    dim3 grid(16384 / BPB);   // 256 blocks, 1 per CU
    dim3 block(128);          // wave 0 = consumer, wave 1 = producer
    sir_scan_kernel<<<grid, block, 0, stream>>>(in, init, out, half);
}